// Round 4
// baseline (151.922 us; speedup 1.0000x reference)
//
#include <hip/hip_runtime.h>
#include <stdint.h>

typedef __attribute__((ext_vector_type(8))) short short8;
typedef __attribute__((ext_vector_type(4))) float f32x4;
typedef __attribute__((ext_vector_type(4))) unsigned int u32x4;
typedef __attribute__((ext_vector_type(4))) unsigned short u16x4;

// B=8, S=2048, D=1024, H=64
// ws: Wb bf16 [192][1024] @0 ; Qw bf16 [16384][64] @393216 ; Kw @+2MB ;
// Vtw [512][2048] @+4MB ; Oa fp32 [16384][64] @6684672 ; la fp32 [16384] @10878976

__device__ __forceinline__ unsigned short f2bf(float f){
  unsigned int u = __builtin_bit_cast(unsigned int, f);
  u = u + 0x7fffu + ((u >> 16) & 1u);
  return (unsigned short)(u >> 16);
}

// ---------------- kernel 0: W -> bf16 pack (rows 0-63 Wq, 64-127 Wk, 128-191 Wv)
__global__ __launch_bounds__(256) void wcvt_k(const float* __restrict__ Wk,
                                              const float* __restrict__ Wq,
                                              const float* __restrict__ Wv,
                                              unsigned short* __restrict__ Wb){
  int t = blockIdx.x * 256 + threadIdx.x;
  int e = t * 8;
  int row = e >> 10, col = e & 1023;
  const float* src = (row < 64)  ? (Wq + row * 1024 + col)
                   : (row < 128) ? (Wk + (row - 64) * 1024 + col)
                   :               (Wv + (row - 128) * 1024 + col);
  f32x4 a = *(const f32x4*)src;
  f32x4 b = *(const f32x4*)(src + 4);
  u16x4 lo = { f2bf(a.x), f2bf(a.y), f2bf(a.z), f2bf(a.w) };
  u16x4 hi = { f2bf(b.x), f2bf(b.y), f2bf(b.z), f2bf(b.w) };
  *(u16x4*)(Wb + e) = lo;
  *(u16x4*)(Wb + e + 4) = hi;
}

// ---------------- kernel 1: QKV GEMM  C[h=192][s=32/block], grid 512 x 256 thr.
// Whole X tile staged once in LDS (ONE barrier, no K-loop barriers); W fragments
// read directly from L2 (384 KB W is L2-resident) with register double-buffer.
__global__ __launch_bounds__(256) void qkv_k(const float* __restrict__ X,
                                             const unsigned short* __restrict__ Wb,
                                             unsigned short* __restrict__ Qw,
                                             unsigned short* __restrict__ Kw,
                                             unsigned short* __restrict__ Vtw){
  __shared__ unsigned short Xl[32][1032];     // 66 KB, +8 pad
  const int t = threadIdx.x, w = t >> 6, l = t & 63, qd = l >> 4, ln = l & 15;
  const int bs0 = blockIdx.x * 32, b = bs0 >> 11, sb = bs0 & 2047;
  const int mset = w * 3;
  // stage whole X tile [32][1024] fp32 -> bf16
  const int xr = t >> 3, xcb = (t & 7) * 8;
#pragma unroll
  for (int i = 0; i < 16; ++i){
    const int col = xcb + i * 64;
    const float* xp = X + (bs0 + xr) * 1024 + col;
    f32x4 xa = *(const f32x4*)xp;
    f32x4 xb = *(const f32x4*)(xp + 4);
    u16x4 lo = { f2bf(xa.x), f2bf(xa.y), f2bf(xa.z), f2bf(xa.w) };
    u16x4 hi = { f2bf(xb.x), f2bf(xb.y), f2bf(xb.z), f2bf(xb.w) };
    *(u16x4*)&Xl[xr][col]     = lo;
    *(u16x4*)&Xl[xr][col + 4] = hi;
  }
  __syncthreads();

  f32x4 acc[3][2];
#pragma unroll
  for (int i = 0; i < 3; ++i)
#pragma unroll
    for (int j = 0; j < 2; ++j) acc[i][j] = (f32x4){0.f, 0.f, 0.f, 0.f};

  // W fragment register double-buffer
  short8 wreg[2][3][2];
#pragma unroll
  for (int i = 0; i < 3; ++i)
#pragma unroll
    for (int ks = 0; ks < 2; ++ks)
      wreg[0][i][ks] = *(const short8*)(Wb + ((mset + i) * 16 + ln) * 1024 + ks * 32 + qd * 8);

  for (int kk = 0; kk < 16; ++kk){
    const int cur = kk & 1, nxt = cur ^ 1;
    if (kk < 15){
      const int k0 = (kk + 1) * 64;
#pragma unroll
      for (int i = 0; i < 3; ++i)
#pragma unroll
        for (int ks = 0; ks < 2; ++ks)
          wreg[nxt][i][ks] = *(const short8*)(Wb + ((mset + i) * 16 + ln) * 1024 + k0 + ks * 32 + qd * 8);
    }
#pragma unroll
    for (int ks = 0; ks < 2; ++ks){
      short8 bfr[2];
#pragma unroll
      for (int j = 0; j < 2; ++j)
        bfr[j] = *(const short8*)&Xl[j * 16 + ln][kk * 64 + ks * 32 + qd * 8];
#pragma unroll
      for (int i = 0; i < 3; ++i)
#pragma unroll
        for (int j = 0; j < 2; ++j)
          acc[i][j] = __builtin_amdgcn_mfma_f32_16x16x32_bf16(wreg[cur][i][ks], bfr[j], acc[i][j], 0, 0, 0);
    }
  }
  // epilogue: D row=qd*4+reg (h-local), col=ln (s-local)
#pragma unroll
  for (int i = 0; i < 3; ++i){
    const int h0 = (mset + i) * 16 + qd * 4;
#pragma unroll
    for (int j = 0; j < 2; ++j){
      const int s = sb + j * 16 + ln;
      f32x4 v = acc[i][j];
      u16x4 pk = { f2bf(v.x), f2bf(v.y), f2bf(v.z), f2bf(v.w) };
      if (h0 < 64){
        *(u16x4*)(Qw + (b * 2048 + s) * 64 + h0) = pk;
      } else if (h0 < 128){
        *(u16x4*)(Kw + (b * 2048 + s) * 64 + (h0 - 64)) = pk;
      } else {
        const int hh = h0 - 128;
        Vtw[(b * 64 + hh + 0) * 2048 + s] = pk.x;
        Vtw[(b * 64 + hh + 1) * 2048 + s] = pk.y;
        Vtw[(b * 64 + hh + 2) * 2048 + s] = pk.z;
        Vtw[(b * 64 + hh + 3) * 2048 + s] = pk.w;
      }
    }
  }
}

// ---------------- kernel 2: causal attention, kv-chunked for occupancy.
// grid 1152 = 8 batch x 144 (qi,chunk) pairs; chunk = 4 j-steps of 64 kv.
// No-max softmax => partial (O,l) merge is a plain sum: atomicAdd into Oa/la.
// 4 waves x 16 q-rows, P wave-private, double-buffered K/V, 1 barrier/j-step.
__global__ __launch_bounds__(256) void attn_k(const unsigned short* __restrict__ Qw,
                                              const unsigned short* __restrict__ Kw,
                                              const unsigned short* __restrict__ Vtw,
                                              float* __restrict__ Oa,
                                              float* __restrict__ la){
  __shared__ unsigned short Kl[2][64][72];
  __shared__ unsigned short Vl[2][64][72];
  __shared__ unsigned short Pl[4][16][72];
  const int t = threadIdx.x, w = t >> 6, l = t & 63, qd = l >> 4, ln = l & 15;
  const int b = blockIdx.x & 7;
  // decode s -> (qi, c): qi in group g has 1+g/1... group g: qi in [4g,4g+4), nch=g+1
  int s = blockIdx.x >> 3, g = 0, base = 0;
  while (s >= base + 4 * (g + 1)){ base += 4 * (g + 1); ++g; }
  const int o = s - base, qi = 4 * g + o / (g + 1), c = o % (g + 1);
  const int jbeg = c * 4, jend = min(jbeg + 3, qi);
  const int q0 = b * 2048 + qi * 64, myq = w * 16, rowloc = qd * 4;
  const float c1 = 0.04508422f;               // log2(e)/32

  short8 aQ[2];
#pragma unroll
  for (int ks = 0; ks < 2; ++ks)
    aQ[ks] = *(const short8*)(Qw + (q0 + myq + ln) * 64 + ks * 32 + qd * 8);

  f32x4 O[4];
#pragma unroll
  for (int i = 0; i < 4; ++i) O[i] = (f32x4){0.f,0.f,0.f,0.f};
  float lacc[4] = {0.f, 0.f, 0.f, 0.f};

  // prologue: stage j=jbeg into buf 0
  {
    const int kb = b * 2048 + jbeg * 64;
#pragma unroll
    for (int i = 0; i < 2; ++i){
      int cgl = t + i * 256, row = cgl >> 3, sub = cgl & 7;
      *(u32x4*)&Kl[0][row][sub * 8] = *(const u32x4*)(Kw + (kb + row) * 64 + sub * 8);
      *(u32x4*)&Vl[0][row][sub * 8] = *(const u32x4*)(Vtw + (b * 64 + row) * 2048 + jbeg * 64 + sub * 8);
    }
  }

  for (int j = jbeg; j <= jend; ++j){
    __syncthreads();
    const int cur = (j - jbeg) & 1, nxt = cur ^ 1;
    u32x4 kreg[2], vreg[2];
    if (j < jend){
      const int kb = b * 2048 + (j + 1) * 64;
#pragma unroll
      for (int i = 0; i < 2; ++i){
        int cgl = t + i * 256, row = cgl >> 3, sub = cgl & 7;
        kreg[i] = *(const u32x4*)(Kw + (kb + row) * 64 + sub * 8);
        vreg[i] = *(const u32x4*)(Vtw + (b * 64 + row) * 2048 + (j + 1) * 64 + sub * 8);
      }
    }
    // S = Q K^T : 16 q-rows x 64 kv
    f32x4 S[4];
#pragma unroll
    for (int nt = 0; nt < 4; ++nt) S[nt] = (f32x4){0.f,0.f,0.f,0.f};
#pragma unroll
    for (int ks = 0; ks < 2; ++ks)
#pragma unroll
      for (int nt = 0; nt < 4; ++nt){
        short8 bK = *(const short8*)&Kl[cur][nt * 16 + ln][ks * 32 + qd * 8];
        S[nt] = __builtin_amdgcn_mfma_f32_16x16x32_bf16(aQ[ks], bK, S[nt], 0, 0, 0);
      }
    // softmax-lite; l accumulated per-lane, reduced once at the end
    const bool dtile = (j == qi);
#pragma unroll
    for (int nt = 0; nt < 4; ++nt){
      const int cl = nt * 16 + ln;
      f32x4 sv = S[nt];
#pragma unroll
      for (int r = 0; r < 4; ++r){
        float p = __builtin_amdgcn_exp2f(sv[r] * c1);
        if (dtile && cl > myq + rowloc + r) p = 0.f;
        lacc[r] += p;
        Pl[w][rowloc + r][cl] = f2bf(p);
      }
    }
    // O += P V
#pragma unroll
    for (int ks = 0; ks < 2; ++ks){
      short8 aP = *(const short8*)&Pl[w][ln][ks * 32 + qd * 8];
#pragma unroll
      for (int ht = 0; ht < 4; ++ht){
        short8 bV = *(const short8*)&Vl[cur][ht * 16 + ln][ks * 32 + qd * 8];
        O[ht] = __builtin_amdgcn_mfma_f32_16x16x32_bf16(aP, bV, O[ht], 0, 0, 0);
      }
    }
    if (j < jend){
#pragma unroll
      for (int i = 0; i < 2; ++i){
        int cgl = t + i * 256, row = cgl >> 3, sub = cgl & 7;
        *(u32x4*)&Kl[nxt][row][sub * 8] = kreg[i];
        *(u32x4*)&Vl[nxt][row][sub * 8] = vreg[i];
      }
    }
  }

  // reduce l across the 16 ln-lanes (masks 1,2,4,8 stay within ln group)
  float lred[4];
#pragma unroll
  for (int r = 0; r < 4; ++r){
    float v = lacc[r];
    v += __shfl_xor(v, 1);
    v += __shfl_xor(v, 2);
    v += __shfl_xor(v, 4);
    v += __shfl_xor(v, 8);
    lred[r] = v;
  }
  // accumulate partials (device-scope atomics)
#pragma unroll
  for (int r = 0; r < 4; ++r){
    const int rowg = q0 + myq + rowloc + r;
#pragma unroll
    for (int ht = 0; ht < 4; ++ht)
      atomicAdd(&Oa[rowg * 64 + ht * 16 + ln], O[ht][r]);
    if (ln == 0) atomicAdd(&la[rowg], lred[r]);
  }
}

// ---------------- kernel 3: normalize  out = Oa / la
__global__ __launch_bounds__(256) void nrm_k(const float* __restrict__ Oa,
                                             const float* __restrict__ la,
                                             float* __restrict__ out){
  const int idx = (blockIdx.x * 256 + threadIdx.x) * 4;
  const int row = idx >> 6;
  const float inv = 1.0f / la[row];
  f32x4 v = *(const f32x4*)(Oa + idx);
  v.x *= inv; v.y *= inv; v.z *= inv; v.w *= inv;
  *(f32x4*)(out + idx) = v;
}

extern "C" void kernel_launch(void* const* d_in, const int* in_sizes, int n_in,
                              void* d_out, int out_size, void* d_ws, size_t ws_size,
                              hipStream_t stream){
  const float* X  = (const float*)d_in[0];
  const float* Wk = (const float*)d_in[1];
  const float* Wq = (const float*)d_in[2];
  const float* Wv = (const float*)d_in[3];
  float* out = (float*)d_out;
  char* ws = (char*)d_ws;
  unsigned short* Wb  = (unsigned short*)(ws);
  unsigned short* Qw  = (unsigned short*)(ws + 393216);
  unsigned short* Kw  = (unsigned short*)(ws + 393216 + 2097152);
  unsigned short* Vtw = (unsigned short*)(ws + 393216 + 2 * 2097152);
  float* Oa = (float*)(ws + 6684672);
  float* la = (float*)(ws + 10878976);

  hipLaunchKernelGGL(wcvt_k, dim3(96),   dim3(256), 0, stream, Wk, Wq, Wv, Wb);
  hipLaunchKernelGGL(qkv_k,  dim3(512),  dim3(256), 0, stream, X, Wb, Qw, Kw, Vtw);
  hipMemsetAsync(Oa, 0, 16384 * 64 * sizeof(float), stream);
  hipMemsetAsync(la, 0, 16384 * sizeof(float), stream);
  hipLaunchKernelGGL(attn_k, dim3(1152), dim3(256), 0, stream, Qw, Kw, Vtw, Oa, la);
  hipLaunchKernelGGL(nrm_k,  dim3(1024), dim3(256), 0, stream, Oa, la, out);
}

// Round 5
// 143.839 us; speedup vs baseline: 1.0562x; 1.0562x over previous
//
#include <hip/hip_runtime.h>
#include <stdint.h>

typedef __attribute__((ext_vector_type(8))) short short8;
typedef __attribute__((ext_vector_type(4))) float f32x4;
typedef __attribute__((ext_vector_type(4))) unsigned int u32x4;
typedef __attribute__((ext_vector_type(4))) unsigned short u16x4;

// B=8, S=2048, D=1024, H=64
// ws: Wb2 bf16 fragment-ordered [12 mtile][16 kchunk][2 ks][64 lane][8] @0 (384 KB)
//     Qw bf16 [16384][64] @393216 ; Kw @2490368 ; Vtw [512][2048] @4587520 ;
//     Op fp32 [4][16384][64] @6684672 (16 MB) ; lp fp32 [4][16384] @23461888

__device__ __forceinline__ unsigned short f2bf(float f){
  unsigned int u = __builtin_bit_cast(unsigned int, f);
  u = u + 0x7fffu + ((u >> 16) & 1u);
  return (unsigned short)(u >> 16);
}

// ---------------- kernel 0: W -> bf16 pack in MFMA-fragment order.
// A-frag for m-tile mt, k-chunk kc, half ks: lane qd*16+ln holds row h=mt*16+ln,
// cols kc*64+ks*32+qd*8 .. +7  => one coalesced 1KB load per fragment in qkv_k.
__global__ __launch_bounds__(256) void wcvt_k(const float* __restrict__ Wk,
                                              const float* __restrict__ Wq,
                                              const float* __restrict__ Wv,
                                              unsigned short* __restrict__ Wb2){
  int t = blockIdx.x * 256 + threadIdx.x;
  int e = t * 8;                                 // 196608 total elems
  int row = e >> 10, col = e & 1023;
  const float* src = (row < 64)  ? (Wq + row * 1024 + col)
                   : (row < 128) ? (Wk + (row - 64) * 1024 + col)
                   :               (Wv + (row - 128) * 1024 + col);
  f32x4 a = *(const f32x4*)src;
  f32x4 b = *(const f32x4*)(src + 4);
  u16x4 lo = { f2bf(a.x), f2bf(a.y), f2bf(a.z), f2bf(a.w) };
  u16x4 hi = { f2bf(b.x), f2bf(b.y), f2bf(b.z), f2bf(b.w) };
  const int mtile = row >> 4, lnn = row & 15;
  const int kchunk = col >> 6, ks = (col >> 5) & 1, qd = (col >> 3) & 3;
  const int lane = qd * 16 + lnn;
  const int off = ((((mtile * 16 + kchunk) * 2 + ks) * 64 + lane)) * 8;
  *(u16x4*)(Wb2 + off)     = lo;
  *(u16x4*)(Wb2 + off + 4) = hi;
}

// ---------------- kernel 1: QKV GEMM  C[h=192][s=16/block], grid 1024 x 256 thr.
// Tiny LDS (4.6 KB) -> ~16 waves/CU. W frags coalesced from L2 (register dbuf),
// X k-chunk staged fp32->bf16 in LDS, double-buffered, 1 barrier/chunk.
__global__ __launch_bounds__(256) void qkv_k(const float* __restrict__ X,
                                             const unsigned short* __restrict__ Wb2,
                                             unsigned short* __restrict__ Qw,
                                             unsigned short* __restrict__ Kw,
                                             unsigned short* __restrict__ Vtw){
  __shared__ unsigned short Xl[2][16][72];
  const int t = threadIdx.x, w = t >> 6, l = t & 63, qd = l >> 4, ln = l & 15;
  const int bs0 = blockIdx.x * 16, b = bs0 >> 11, sb = bs0 & 2047;
  const int mset = w * 3;
  const int xr = t >> 4, xc = (t & 15) * 4;      // 4 floats/thread per chunk

  f32x4 acc[3];
#pragma unroll
  for (int i = 0; i < 3; ++i) acc[i] = (f32x4){0.f, 0.f, 0.f, 0.f};

  short8 wreg[2][3][2];
#pragma unroll
  for (int i = 0; i < 3; ++i)
#pragma unroll
    for (int ks = 0; ks < 2; ++ks)
      wreg[0][i][ks] = *(const short8*)(Wb2 + ((((mset + i) * 16 + 0) * 2 + ks) * 64 + l) * 8);
  {
    f32x4 xa = *(const f32x4*)(X + (bs0 + xr) * 1024 + xc);
    u16x4 pk = { f2bf(xa.x), f2bf(xa.y), f2bf(xa.z), f2bf(xa.w) };
    *(u16x4*)&Xl[0][xr][xc] = pk;
  }

  for (int kk = 0; kk < 16; ++kk){
    __syncthreads();
    const int cur = kk & 1, nxt = cur ^ 1;
    f32x4 xa;
    if (kk < 15){
      xa = *(const f32x4*)(X + (bs0 + xr) * 1024 + (kk + 1) * 64 + xc);
#pragma unroll
      for (int i = 0; i < 3; ++i)
#pragma unroll
        for (int ks = 0; ks < 2; ++ks)
          wreg[nxt][i][ks] = *(const short8*)(Wb2 + ((((mset + i) * 16 + kk + 1) * 2 + ks) * 64 + l) * 8);
    }
#pragma unroll
    for (int ks = 0; ks < 2; ++ks){
      short8 bfr = *(const short8*)&Xl[cur][ln][ks * 32 + qd * 8];
#pragma unroll
      for (int i = 0; i < 3; ++i)
        acc[i] = __builtin_amdgcn_mfma_f32_16x16x32_bf16(wreg[cur][i][ks], bfr, acc[i], 0, 0, 0);
    }
    if (kk < 15){
      u16x4 pk = { f2bf(xa.x), f2bf(xa.y), f2bf(xa.z), f2bf(xa.w) };
      *(u16x4*)&Xl[nxt][xr][xc] = pk;
    }
  }
  // epilogue: D reg r -> h = (mset+i)*16 + qd*4 + r, col s = sb + ln
  const int s = sb + ln;
#pragma unroll
  for (int i = 0; i < 3; ++i){
    const int h0 = (mset + i) * 16 + qd * 4;
    f32x4 v = acc[i];
    u16x4 pk = { f2bf(v.x), f2bf(v.y), f2bf(v.z), f2bf(v.w) };
    if (h0 < 64){
      *(u16x4*)(Qw + (b * 2048 + s) * 64 + h0) = pk;
    } else if (h0 < 128){
      *(u16x4*)(Kw + (b * 2048 + s) * 64 + (h0 - 64)) = pk;
    } else {
      const int hh = h0 - 128;
      Vtw[(b * 64 + hh + 0) * 2048 + s] = pk.x;
      Vtw[(b * 64 + hh + 1) * 2048 + s] = pk.y;
      Vtw[(b * 64 + hh + 2) * 2048 + s] = pk.z;
      Vtw[(b * 64 + hh + 3) * 2048 + s] = pk.w;
    }
  }
}

// ---------------- kernel 2: causal attention, kv-chunked (8 j-steps/chunk).
// grid 640 = 8 batch x 80 (qi,c) pairs, longest qi first. Partials written to
// PRIVATE per-chunk buffers (no atomics, no memset needed). 4 waves x 16 q-rows,
// P wave-private, double-buffered K/V, 1 barrier/j-step, no-max softmax.
__global__ __launch_bounds__(256) void attn_k(const unsigned short* __restrict__ Qw,
                                              const unsigned short* __restrict__ Kw,
                                              const unsigned short* __restrict__ Vtw,
                                              float* __restrict__ Op,
                                              float* __restrict__ lp){
  __shared__ unsigned short Kl[2][64][72];
  __shared__ unsigned short Vl[2][64][72];
  __shared__ unsigned short Pl[4][16][72];
  const int t = threadIdx.x, w = t >> 6, l = t & 63, qd = l >> 4, ln = l & 15;
  const int b = blockIdx.x & 7;
  const int sp = blockIdx.x >> 3;               // 0..79, longest qi first
  int qi, c;
  if (sp < 32){ qi = 31 - (sp >> 2); c = sp & 3; }
  else if (sp < 56){ int u = sp - 32; int d = u / 3; qi = 23 - d; c = u - d * 3; }
  else if (sp < 72){ int u = sp - 56; qi = 15 - (u >> 1); c = u & 1; }
  else { qi = 7 - (sp - 72); c = 0; }
  const int jbeg = c * 8, jend = min(jbeg + 7, qi);
  const int q0 = b * 2048 + qi * 64, myq = w * 16, rowloc = qd * 4;
  const float c1 = 0.04508422f;                 // log2(e)/32

  short8 aQ[2];
#pragma unroll
  for (int ks = 0; ks < 2; ++ks)
    aQ[ks] = *(const short8*)(Qw + (q0 + myq + ln) * 64 + ks * 32 + qd * 8);

  f32x4 O[4];
#pragma unroll
  for (int i = 0; i < 4; ++i) O[i] = (f32x4){0.f,0.f,0.f,0.f};
  float lacc[4] = {0.f, 0.f, 0.f, 0.f};

  {
    const int kb = b * 2048 + jbeg * 64;
#pragma unroll
    for (int i = 0; i < 2; ++i){
      int cgl = t + i * 256, row = cgl >> 3, sub = cgl & 7;
      *(u32x4*)&Kl[0][row][sub * 8] = *(const u32x4*)(Kw + (kb + row) * 64 + sub * 8);
      *(u32x4*)&Vl[0][row][sub * 8] = *(const u32x4*)(Vtw + (b * 64 + row) * 2048 + jbeg * 64 + sub * 8);
    }
  }

  for (int j = jbeg; j <= jend; ++j){
    __syncthreads();
    const int cur = (j - jbeg) & 1, nxt = cur ^ 1;
    u32x4 kreg[2], vreg[2];
    if (j < jend){
      const int kb = b * 2048 + (j + 1) * 64;
#pragma unroll
      for (int i = 0; i < 2; ++i){
        int cgl = t + i * 256, row = cgl >> 3, sub = cgl & 7;
        kreg[i] = *(const u32x4*)(Kw + (kb + row) * 64 + sub * 8);
        vreg[i] = *(const u32x4*)(Vtw + (b * 64 + row) * 2048 + (j + 1) * 64 + sub * 8);
      }
    }
    f32x4 S[4];
#pragma unroll
    for (int nt = 0; nt < 4; ++nt) S[nt] = (f32x4){0.f,0.f,0.f,0.f};
#pragma unroll
    for (int ks = 0; ks < 2; ++ks)
#pragma unroll
      for (int nt = 0; nt < 4; ++nt){
        short8 bK = *(const short8*)&Kl[cur][nt * 16 + ln][ks * 32 + qd * 8];
        S[nt] = __builtin_amdgcn_mfma_f32_16x16x32_bf16(aQ[ks], bK, S[nt], 0, 0, 0);
      }
    const bool dtile = (j == qi);
#pragma unroll
    for (int nt = 0; nt < 4; ++nt){
      const int cl = nt * 16 + ln;
      f32x4 sv = S[nt];
#pragma unroll
      for (int r = 0; r < 4; ++r){
        float p = __builtin_amdgcn_exp2f(sv[r] * c1);
        if (dtile && cl > myq + rowloc + r) p = 0.f;
        lacc[r] += p;
        Pl[w][rowloc + r][cl] = f2bf(p);
      }
    }
#pragma unroll
    for (int ks = 0; ks < 2; ++ks){
      short8 aP = *(const short8*)&Pl[w][ln][ks * 32 + qd * 8];
#pragma unroll
      for (int ht = 0; ht < 4; ++ht){
        short8 bV = *(const short8*)&Vl[cur][ht * 16 + ln][ks * 32 + qd * 8];
        O[ht] = __builtin_amdgcn_mfma_f32_16x16x32_bf16(aP, bV, O[ht], 0, 0, 0);
      }
    }
    if (j < jend){
#pragma unroll
      for (int i = 0; i < 2; ++i){
        int cgl = t + i * 256, row = cgl >> 3, sub = cgl & 7;
        *(u32x4*)&Kl[nxt][row][sub * 8] = kreg[i];
        *(u32x4*)&Vl[nxt][row][sub * 8] = vreg[i];
      }
    }
  }

  // reduce l across the 16 ln-lanes
  float lred[4];
#pragma unroll
  for (int r = 0; r < 4; ++r){
    float v = lacc[r];
    v += __shfl_xor(v, 1);
    v += __shfl_xor(v, 2);
    v += __shfl_xor(v, 4);
    v += __shfl_xor(v, 8);
    lred[r] = v;
  }
  // plain stores to private chunk-c partial buffers
  float* Opc = Op + c * 1048576;      // 16384*64
  float* lpc = lp + c * 16384;
#pragma unroll
  for (int r = 0; r < 4; ++r){
    const int rowg = q0 + myq + rowloc + r;
#pragma unroll
    for (int ht = 0; ht < 4; ++ht)
      Opc[rowg * 64 + ht * 16 + ln] = O[ht][r];
    if (ln == 0) lpc[rowg] = lred[r];
  }
}

// ---------------- kernel 3: sum valid chunk partials + normalize
__global__ __launch_bounds__(256) void nrm_k(const float* __restrict__ Op,
                                             const float* __restrict__ lp,
                                             float* __restrict__ out){
  const int idx = (blockIdx.x * 256 + threadIdx.x) * 4;
  const int row = idx >> 6;
  const int qi = (row >> 6) & 31;
  const int nch = (qi >> 3) + 1;                // valid chunks for this row
  f32x4 s = (f32x4){0.f,0.f,0.f,0.f};
  float lsum = 0.f;
  for (int c = 0; c < nch; ++c){
    f32x4 v = *(const f32x4*)(Op + c * 1048576 + idx);
    s.x += v.x; s.y += v.y; s.z += v.z; s.w += v.w;
    lsum += lp[c * 16384 + row];
  }
  const float inv = 1.0f / lsum;
  s.x *= inv; s.y *= inv; s.z *= inv; s.w *= inv;
  *(f32x4*)(out + idx) = s;
}

extern "C" void kernel_launch(void* const* d_in, const int* in_sizes, int n_in,
                              void* d_out, int out_size, void* d_ws, size_t ws_size,
                              hipStream_t stream){
  const float* X  = (const float*)d_in[0];
  const float* Wk = (const float*)d_in[1];
  const float* Wq = (const float*)d_in[2];
  const float* Wv = (const float*)d_in[3];
  float* out = (float*)d_out;
  char* ws = (char*)d_ws;
  unsigned short* Wb2 = (unsigned short*)(ws);
  unsigned short* Qw  = (unsigned short*)(ws + 393216);
  unsigned short* Kw  = (unsigned short*)(ws + 2490368);
  unsigned short* Vtw = (unsigned short*)(ws + 4587520);
  float* Op = (float*)(ws + 6684672);
  float* lp = (float*)(ws + 23461888);

  hipLaunchKernelGGL(wcvt_k, dim3(96),   dim3(256), 0, stream, Wk, Wq, Wv, Wb2);
  hipLaunchKernelGGL(qkv_k,  dim3(1024), dim3(256), 0, stream, X, Wb2, Qw, Kw, Vtw);
  hipLaunchKernelGGL(attn_k, dim3(640),  dim3(256), 0, stream, Qw, Kw, Vtw, Op, lp);
  hipLaunchKernelGGL(nrm_k,  dim3(1024), dim3(256), 0, stream, Op, lp, out);
}